// Round 3
// baseline (247.822 us; speedup 1.0000x reference)
//
#include <hip/hip_runtime.h>
#include <hip/hip_bf16.h>

// DomainEncoder: 8-expert MoE MLP, N=32768, 256 -> 1024 (LN+ReLU) -> 256.
// Pipeline (8 launches):
//   1. transpose W1,W2 -> bf16 [N,K] ("B^T" layout); first transpose also zeros counters
//   2. counting-sort rows by domain: histo -> make_meta (also pads perm=-1)
//      -> assign_pos (block-aggregated atomics) -> copy_rows (coalesced gather)
//   3. gemm_ln: h = LN(x_s @ W1[d]^T + b1)*gamma+beta, ReLU  -- fused, 64x1024 block
//   4. gemm_bt: out = g @ W2[d]^T + b2, scattered back through perm (fp32 out)

#define ND 8
#define NROWS 32768
#define DIN 256
#define DHID 1024
#define DOUT 256
#define MPAD 33792          // 32768 + 8*128 worst-case padding
#define NTILES 264          // 256 + 8 worst-case 128-row tiles

typedef short short8 __attribute__((ext_vector_type(8)));
typedef float floatx4 __attribute__((ext_vector_type(4)));

__device__ __forceinline__ unsigned short f2bf(float f) {
    unsigned u = __builtin_bit_cast(unsigned, f);
    unsigned r = u + 0x7fff + ((u >> 16) & 1);   // RNE (inputs finite)
    return (unsigned short)(r >> 16);
}
__device__ __forceinline__ float bf2f(unsigned short h) {
    unsigned u = ((unsigned)h) << 16;
    return __builtin_bit_cast(float, u);
}

#define GLDS16(gp, lp) __builtin_amdgcn_global_load_lds( \
    (const __attribute__((address_space(1))) void*)(gp), \
    (__attribute__((address_space(3))) void*)(lp), 16, 0, 0)

// ---------------- 1. weight transpose fp32[R,C] -> bf16[C,R], per-domain z ----
// Also zeros the 16 sort counters from its first block (cnt may be null).
__global__ void transpose_bf16(const float* __restrict__ in,
                               unsigned short* __restrict__ out,
                               int R, int C, int* __restrict__ cnt) {
    __shared__ float t[32][33];
    const int z = blockIdx.z;
    const int c0 = blockIdx.x * 32, r0 = blockIdx.y * 32;
    const int tx = threadIdx.x & 31, ty = threadIdx.x >> 5;   // 32x8
    if (cnt && blockIdx.x == 0 && blockIdx.y == 0 && z == 0 && threadIdx.x < 16)
        cnt[threadIdx.x] = 0;
    const float* src = in + (size_t)z * R * C;
    unsigned short* dst = out + (size_t)z * R * C;
#pragma unroll
    for (int i = 0; i < 32; i += 8)
        t[ty + i][tx] = src[(size_t)(r0 + ty + i) * C + c0 + tx];
    __syncthreads();
#pragma unroll
    for (int i = 0; i < 32; i += 8)
        dst[(size_t)(c0 + ty + i) * R + r0 + tx] = f2bf(t[tx][ty + i]);
}

// ---------------- 2a. histogram (block-aggregated atomics) --------------------
__global__ void histo(const int* __restrict__ dt, int* __restrict__ counts) {
    __shared__ int lc[ND];
    if (threadIdx.x < ND) lc[threadIdx.x] = 0;
    __syncthreads();
    int i = blockIdx.x * 256 + threadIdx.x;      // grid covers exactly NROWS
    atomicAdd(&lc[dt[i]], 1);
    __syncthreads();
    if (threadIdx.x < ND) atomicAdd(&counts[threadIdx.x], lc[threadIdx.x]);
}

// ---------------- 2b. offsets + tile metadata + pad perm (single thread) ------
__global__ void make_meta(const int* __restrict__ counts, int* __restrict__ cursors,
                          int2* __restrict__ meta, int* __restrict__ perm) {
    if (threadIdx.x == 0 && blockIdx.x == 0) {
        int off = 0, t = 0;
        for (int d = 0; d < ND; d++) {
            cursors[d] = off;
            int nt = (counts[d] + 127) >> 7;
            for (int i = 0; i < nt; i++) meta[t++] = make_int2(d, off + (i << 7));
            for (int p = off + counts[d]; p < off + (nt << 7); p++) perm[p] = -1;
            off += nt << 7;
        }
        for (; t < NTILES; t++) meta[t] = make_int2(-1, 0);
    }
}

// ---------------- 2c. position assignment: 8 global atomics per 256 rows ------
__global__ __launch_bounds__(256)
void assign_pos(const int* __restrict__ dt, int* __restrict__ cursors,
                int* __restrict__ perm, int* __restrict__ pos) {
    __shared__ int lcnt[ND];
    __shared__ int lbase[ND];
    const int tid = threadIdx.x;
    if (tid < ND) lcnt[tid] = 0;
    __syncthreads();
    const int r = blockIdx.x * 256 + tid;
    const int d = dt[r];
    const int myrank = atomicAdd(&lcnt[d], 1);   // LDS atomic: cheap
    __syncthreads();
    if (tid < ND && lcnt[tid] > 0)
        lbase[tid] = atomicAdd(&cursors[tid], lcnt[tid]);  // 8 global atomics/block
    __syncthreads();
    const int p = lbase[d] + myrank;
    pos[r] = p;
    perm[p] = r;
}

// ---------------- 2d. gather copy: one wave per row, coalesced ---------------
__global__ __launch_bounds__(256)
void copy_rows(const float* __restrict__ x, const int* __restrict__ pos,
               unsigned short* __restrict__ xs) {
    const int tid = threadIdx.x;
    const int lane = tid & 63;
    const int r = blockIdx.x * 4 + (tid >> 6);           // 4 rows per block
    const int p = pos[r];
    float4 v = ((const float4*)(x + (size_t)r * DIN))[lane];   // 16B/lane read
    ushort4 o;
    o.x = f2bf(v.x); o.y = f2bf(v.y); o.z = f2bf(v.z); o.w = f2bf(v.w);
    ((ushort4*)(xs + (size_t)p * DIN))[lane] = o;              // 8B/lane write
}

// ---------------- 3. fused GEMM-A + bias + LayerNorm + ReLU ------------------
// Block: 64 rows x 1024 cols, 8 waves (512 thr). Wave w: cols [w*128, w*128+128),
// all 64 rows -> acc[4][8] (i=row-tile, j=col-tile), mfma_16x16x32_bf16.
// LN over the full 1024 cols lives inside the block: in-reg j-sum -> shfl over
// 16-lane col group -> 8-wave LDS reduction -> normalize -> bf16 H write.
__global__ __launch_bounds__(512, 2)
void gemm_ln(const unsigned short* __restrict__ A,      // XS [MPAD,256]
             const unsigned short* __restrict__ Bt,     // W1T [ND,1024,256]
             const float* __restrict__ bias,            // b1 [ND,1024]
             const float* __restrict__ gamma,
             const float* __restrict__ beta,
             const int2* __restrict__ meta,
             unsigned short* __restrict__ H) {
    const int2 md = meta[blockIdx.x >> 1];
    const int dom = md.x;
    if (dom < 0) return;
    const int m0 = md.y + (blockIdx.x & 1) * 64;

    __shared__ unsigned short As[64 * 32];     //  4 KB [m][k]
    __shared__ unsigned short Bs[1024 * 32];   // 64 KB [n][k]
    __shared__ float red_s[64][9];             // per-row sum partials (+pad)
    __shared__ float red_q[64][9];             // per-row sumsq partials
    __shared__ float mu_s[64], rs_s[64];

    const int tid = threadIdx.x;
    const int lane = tid & 63;
    const int w = tid >> 6;                    // wave 0..7
    const int c16 = lane & 15;
    const int quad = lane >> 4;

    const unsigned short* Abase = A + (size_t)m0 * DIN;
    const unsigned short* Bbase = Bt + (size_t)dom * DHID * DIN;

    floatx4 acc[4][8];
#pragma unroll
    for (int i = 0; i < 4; i++)
#pragma unroll
        for (int j = 0; j < 8; j++) acc[i][j] = 0.f;

    for (int k0 = 0; k0 < DIN; k0 += 32) {
        // stage B slab 1024x32 (4096 16B chunks = 8 wave-loads/wave)
#pragma unroll
        for (int it = 0; it < 8; ++it) {
            const int c = (w * 8 + it) * 64 + lane;     // chunk id
            const int n = c >> 2, kc = c & 3;
            GLDS16(Bbase + (size_t)n * DIN + k0 + kc * 8, &Bs[(w * 8 + it) * 512]);
        }
        // stage A slab 64x32 (256 chunks = 4 wave-loads)
        if (w < 4) {
            const int c = w * 64 + lane;
            const int m = c >> 2, kc = c & 3;
            GLDS16(Abase + (size_t)m * DIN + k0 + kc * 8, &As[w * 512]);
        }
        __syncthreads();

        const int kk = quad * 8;
        short8 a[4], b[8];
#pragma unroll
        for (int i = 0; i < 4; i++)
            a[i] = *(const short8*)&As[(i * 16 + c16) * 32 + kk];
#pragma unroll
        for (int j = 0; j < 8; j++)
            b[j] = *(const short8*)&Bs[(w * 128 + j * 16 + c16) * 32 + kk];
#pragma unroll
        for (int i = 0; i < 4; i++)
#pragma unroll
            for (int j = 0; j < 8; j++)
                acc[i][j] = __builtin_amdgcn_mfma_f32_16x16x32_bf16(a[i], b[j], acc[i][j], 0, 0, 0);
        __syncthreads();
    }

    // ---- bias add + per-row sum/sumsq over this wave's 128 cols ----
    float bv[8];
#pragma unroll
    for (int j = 0; j < 8; j++) bv[j] = bias[dom * DHID + w * 128 + j * 16 + c16];

#pragma unroll
    for (int i = 0; i < 4; i++) {
#pragma unroll
        for (int r = 0; r < 4; r++) {
            float s = 0.f, q = 0.f;
#pragma unroll
            for (int j = 0; j < 8; j++) {
                float v = acc[i][j][r] + bv[j];
                acc[i][j][r] = v;
                s += v; q += v * v;
            }
#pragma unroll
            for (int o = 1; o < 16; o <<= 1) {    // reduce across the 16 col lanes
                s += __shfl_xor(s, o, 64);
                q += __shfl_xor(q, o, 64);
            }
            if (c16 == 0) {
                const int row = i * 16 + quad * 4 + r;
                red_s[row][w] = s;
                red_q[row][w] = q;
            }
        }
    }
    __syncthreads();

    if (tid < 64) {   // one thread per row: combine 8 wave partials
        float s = 0.f, q = 0.f;
#pragma unroll
        for (int ww = 0; ww < 8; ww++) { s += red_s[tid][ww]; q += red_q[tid][ww]; }
        const float inv = 1.0f / (float)DHID;
        const float mu = s * inv;
        const float var = fmaxf(q * inv - mu * mu, 0.f);
        mu_s[tid] = mu;
        rs_s[tid] = rsqrtf(var + 1e-5f);
    }
    __syncthreads();

    float gv[8], btv[8];
#pragma unroll
    for (int j = 0; j < 8; j++) {
        gv[j] = gamma[dom * DHID + w * 128 + j * 16 + c16];
        btv[j] = beta[dom * DHID + w * 128 + j * 16 + c16];
    }
#pragma unroll
    for (int i = 0; i < 4; i++) {
#pragma unroll
        for (int r = 0; r < 4; r++) {
            const int row = i * 16 + quad * 4 + r;
            const float mu = mu_s[row], rs = rs_s[row];
            unsigned short* hrow = H + (size_t)(m0 + row) * DHID + w * 128;
#pragma unroll
            for (int j = 0; j < 8; j++) {
                float v = (acc[i][j][r] - mu) * rs * gv[j] + btv[j];
                hrow[j * 16 + c16] = f2bf(fmaxf(v, 0.f));
            }
        }
    }
}

// ---------------- 4. GEMM-B, m97 structure, scatter epilogue -----------------
// C[128x128] per block, 4 waves 2x2, each wave 64x64 = 4x4 mfma_16x16x32_bf16.
__global__ __launch_bounds__(256, 2)
void gemm_bt(const unsigned short* __restrict__ A,      // H [MPAD,1024]
             const unsigned short* __restrict__ Bt,     // W2T [ND,256,1024]
             const float* __restrict__ bias,            // b2 [ND,256]
             const int2* __restrict__ meta,
             const int* __restrict__ perm,
             float* __restrict__ Cf,
             const int Ntot, const int K) {
    const int2 md = meta[blockIdx.x];
    const int dom = md.x;
    if (dom < 0) return;
    const int m0 = md.y;
    const int n0 = blockIdx.y * 128;

    __shared__ unsigned short As[128 * 32];   // [m][k], 8 KB
    __shared__ unsigned short Bs[128 * 32];   // [n][k], 8 KB

    const int tid = threadIdx.x;
    const int lane = tid & 63;
    const int w = tid >> 6;            // wave id 0..3
    const int wr = w >> 1, wc = w & 1; // 2x2 wave grid

    const unsigned short* Abase = A + (size_t)m0 * K;
    const unsigned short* Bbase = Bt + (size_t)dom * Ntot * K + (size_t)n0 * K;

    floatx4 acc[4][4];
#pragma unroll
    for (int i = 0; i < 4; i++)
#pragma unroll
        for (int j = 0; j < 4; j++) acc[i][j] = 0.f;

    for (int k0 = 0; k0 < K; k0 += 32) {
#pragma unroll
        for (int it = 0; it < 2; ++it) {
            const int c = w * 128 + it * 64 + lane;
            const int m = c >> 2, kc = c & 3;
            GLDS16(Abase + (size_t)m * K + k0 + kc * 8, &As[(w * 128 + it * 64) * 8]);
            GLDS16(Bbase + (size_t)m * K + k0 + kc * 8, &Bs[(w * 128 + it * 64) * 8]);
        }
        __syncthreads();

        short8 a[4], b[4];
        const int kk = (lane >> 4) * 8;
#pragma unroll
        for (int i = 0; i < 4; i++) {
            const int m = wr * 64 + i * 16 + (lane & 15);
            a[i] = *(const short8*)&As[m * 32 + kk];
            const int n = wc * 64 + i * 16 + (lane & 15);
            b[i] = *(const short8*)&Bs[n * 32 + kk];
        }
#pragma unroll
        for (int i = 0; i < 4; i++)
#pragma unroll
            for (int j = 0; j < 4; j++)
                acc[i][j] = __builtin_amdgcn_mfma_f32_16x16x32_bf16(a[i], b[j], acc[i][j], 0, 0, 0);
        __syncthreads();
    }

    // epilogue: C/D layout col=lane&15, row=(lane>>4)*4+reg  [m89-verified]
    const int quad = lane >> 4;
#pragma unroll
    for (int i = 0; i < 4; i++) {
        const int rowbase = m0 + wr * 64 + i * 16 + quad * 4;
#pragma unroll
        for (int r = 0; r < 4; r++) {
            const int orig = perm[rowbase + r];
            if (orig < 0) continue;     // padding row
#pragma unroll
            for (int j = 0; j < 4; j++) {
                const int col = n0 + wc * 64 + j * 16 + (lane & 15);
                Cf[(size_t)orig * Ntot + col] = acc[i][j][r] + bias[dom * Ntot + col];
            }
        }
    }
}

// ---------------- launch ------------------------------------------------------
extern "C" void kernel_launch(void* const* d_in, const int* in_sizes, int n_in,
                              void* d_out, int out_size, void* d_ws, size_t ws_size,
                              hipStream_t stream) {
    const float* x = (const float*)d_in[0];
    const int* dt = (const int*)d_in[1];
    const float* W1 = (const float*)d_in[2];
    const float* b1 = (const float*)d_in[3];
    const float* gamma = (const float*)d_in[4];
    const float* beta = (const float*)d_in[5];
    const float* W2 = (const float*)d_in[6];
    const float* b2 = (const float*)d_in[7];
    float* out = (float*)d_out;

    char* ws = (char*)d_ws;
    size_t off = 0;
    auto take = [&](size_t nbytes) -> char* {
        char* p = ws + off;
        off = (off + nbytes + 255) & ~(size_t)255;
        return p;
    };
    unsigned short* W1T = (unsigned short*)take((size_t)ND * DHID * DIN * 2);   // [8,1024,256]
    unsigned short* W2T = (unsigned short*)take((size_t)ND * DOUT * DHID * 2);  // [8,256,1024]
    unsigned short* XS  = (unsigned short*)take((size_t)MPAD * DIN * 2);
    unsigned short* H   = (unsigned short*)take((size_t)MPAD * DHID * 2);
    int* PERM   = (int*)take(MPAD * 4);
    int* POS    = (int*)take(NROWS * 4);
    int* CNT    = (int*)take(64);            // counts[8] then cursors[8]
    int2* META  = (int2*)take(NTILES * 8);
    (void)ws_size; (void)n_in; (void)in_sizes; (void)out_size;

    int* COUNTS = CNT;
    int* CURSORS = CNT + 8;

    transpose_bf16<<<dim3(DHID / 32, DIN / 32, ND), 256, 0, stream>>>(W1, W1T, DIN, DHID, CNT);
    transpose_bf16<<<dim3(DOUT / 32, DHID / 32, ND), 256, 0, stream>>>(W2, W2T, DHID, DOUT, nullptr);
    histo<<<NROWS / 256, 256, 0, stream>>>(dt, COUNTS);
    make_meta<<<1, 1, 0, stream>>>(COUNTS, CURSORS, META, PERM);
    assign_pos<<<NROWS / 256, 256, 0, stream>>>(dt, CURSORS, PERM, POS);
    copy_rows<<<NROWS / 4, 256, 0, stream>>>(x, POS, XS);
    gemm_ln<<<NTILES * 2, 512, 0, stream>>>(XS, W1T, b1, gamma, beta, META, H);
    gemm_bt<<<dim3(NTILES, DOUT / 128), 256, 0, stream>>>(
        H, W2T, b2, META, PERM, out, DOUT, DHID);
}

// Round 4
// 229.157 us; speedup vs baseline: 1.0815x; 1.0815x over previous
//
#include <hip/hip_runtime.h>
#include <hip/hip_bf16.h>

// DomainEncoder: 8-expert MoE MLP, N=32768, 256 -> 1024 (LN+ReLU) -> 256.
// Pipeline (8 launches), all GEMMs in the proven 128x128 m97 structure:
//   1. transpose W1,W2 -> bf16 [N,K]; first transpose also zeros sort counters
//   2. counting-sort rows: histo -> make_meta (pads perm=-1) -> assign_pos
//      (block-aggregated atomics) -> copy_rows (coalesced gather, fp32->bf16)
//   3. gemm_a: H = x_s @ W1[d]^T + b1 (bf16), plus per-row partial sum/sumsq
//      -> stats[16][MPAD] (one plain store per slot, no atomics, no init)
//   4. gemm_b_ln: A-staging applies LN(stats)+gamma/beta+ReLU in a VGPR
//      round-trip (ds_write_b128), then out = g @ W2[d]^T + b2 scattered via perm

#define ND 8
#define NROWS 32768
#define DIN 256
#define DHID 1024
#define DOUT 256
#define MPAD 33792          // 32768 + 8*128 worst-case padding
#define NTILES 264          // 256 + 8 worst-case 128-row tiles

typedef short short8 __attribute__((ext_vector_type(8)));
typedef unsigned short ushort8v __attribute__((ext_vector_type(8)));
typedef float floatx4 __attribute__((ext_vector_type(4)));

__device__ __forceinline__ unsigned short f2bf(float f) {
    unsigned u = __builtin_bit_cast(unsigned, f);
    unsigned r = u + 0x7fff + ((u >> 16) & 1);   // RNE (inputs finite)
    return (unsigned short)(r >> 16);
}
__device__ __forceinline__ float bf2f(unsigned short h) {
    unsigned u = ((unsigned)h) << 16;
    return __builtin_bit_cast(float, u);
}

#define GLDS16(gp, lp) __builtin_amdgcn_global_load_lds( \
    (const __attribute__((address_space(1))) void*)(gp), \
    (__attribute__((address_space(3))) void*)(lp), 16, 0, 0)

// ---------------- 1. weight transpose fp32[R,C] -> bf16[C,R], per-domain z ----
__global__ void transpose_bf16(const float* __restrict__ in,
                               unsigned short* __restrict__ out,
                               int R, int C, int* __restrict__ cnt) {
    __shared__ float t[32][33];
    const int z = blockIdx.z;
    const int c0 = blockIdx.x * 32, r0 = blockIdx.y * 32;
    const int tx = threadIdx.x & 31, ty = threadIdx.x >> 5;   // 32x8
    if (cnt && blockIdx.x == 0 && blockIdx.y == 0 && z == 0 && threadIdx.x < 16)
        cnt[threadIdx.x] = 0;
    const float* src = in + (size_t)z * R * C;
    unsigned short* dst = out + (size_t)z * R * C;
#pragma unroll
    for (int i = 0; i < 32; i += 8)
        t[ty + i][tx] = src[(size_t)(r0 + ty + i) * C + c0 + tx];
    __syncthreads();
#pragma unroll
    for (int i = 0; i < 32; i += 8)
        dst[(size_t)(c0 + ty + i) * R + r0 + tx] = f2bf(t[tx][ty + i]);
}

// ---------------- 2a. histogram (block-aggregated atomics) --------------------
__global__ void histo(const int* __restrict__ dt, int* __restrict__ counts) {
    __shared__ int lc[ND];
    if (threadIdx.x < ND) lc[threadIdx.x] = 0;
    __syncthreads();
    int i = blockIdx.x * 256 + threadIdx.x;      // grid covers exactly NROWS
    atomicAdd(&lc[dt[i]], 1);
    __syncthreads();
    if (threadIdx.x < ND) atomicAdd(&counts[threadIdx.x], lc[threadIdx.x]);
}

// ---------------- 2b. offsets + tile metadata + pad perm (single thread) ------
__global__ void make_meta(const int* __restrict__ counts, int* __restrict__ cursors,
                          int2* __restrict__ meta, int* __restrict__ perm) {
    if (threadIdx.x == 0 && blockIdx.x == 0) {
        int off = 0, t = 0;
        for (int d = 0; d < ND; d++) {
            cursors[d] = off;
            int nt = (counts[d] + 127) >> 7;
            for (int i = 0; i < nt; i++) meta[t++] = make_int2(d, off + (i << 7));
            for (int p = off + counts[d]; p < off + (nt << 7); p++) perm[p] = -1;
            off += nt << 7;
        }
        for (; t < NTILES; t++) meta[t] = make_int2(-1, 0);
    }
}

// ---------------- 2c. position assignment: 8 global atomics per 256 rows ------
__global__ __launch_bounds__(256)
void assign_pos(const int* __restrict__ dt, int* __restrict__ cursors,
                int* __restrict__ perm, int* __restrict__ pos) {
    __shared__ int lcnt[ND];
    __shared__ int lbase[ND];
    const int tid = threadIdx.x;
    if (tid < ND) lcnt[tid] = 0;
    __syncthreads();
    const int r = blockIdx.x * 256 + tid;
    const int d = dt[r];
    const int myrank = atomicAdd(&lcnt[d], 1);   // LDS atomic: cheap
    __syncthreads();
    if (tid < ND && lcnt[tid] > 0)
        lbase[tid] = atomicAdd(&cursors[tid], lcnt[tid]);  // 8 global atomics/block
    __syncthreads();
    const int p = lbase[d] + myrank;
    pos[r] = p;
    perm[p] = r;
}

// ---------------- 2d. gather copy: one wave per row, coalesced ---------------
__global__ __launch_bounds__(256)
void copy_rows(const float* __restrict__ x, const int* __restrict__ pos,
               unsigned short* __restrict__ xs) {
    const int tid = threadIdx.x;
    const int lane = tid & 63;
    const int r = blockIdx.x * 4 + (tid >> 6);           // 4 rows per block
    const int p = pos[r];
    float4 v = ((const float4*)(x + (size_t)r * DIN))[lane];   // 16B/lane read
    ushort4 o;
    o.x = f2bf(v.x); o.y = f2bf(v.y); o.z = f2bf(v.z); o.w = f2bf(v.w);
    ((ushort4*)(xs + (size_t)p * DIN))[lane] = o;              // 8B/lane write
}

// ---------------- 3. GEMM-A (m97 128x128) + bias + per-row stats -------------
// stats slab index = blockIdx.y*2 + wc (16 slabs); each slot written once.
__global__ __launch_bounds__(256, 2)
void gemm_a(const unsigned short* __restrict__ A,      // XS [MPAD,256]
            const unsigned short* __restrict__ Bt,     // W1T [ND,1024,256]
            const float* __restrict__ bias,            // b1 [ND,1024]
            const int2* __restrict__ meta,
            unsigned short* __restrict__ H,            // [MPAD,1024]
            float2* __restrict__ stats) {              // [16][MPAD]
    const int2 md = meta[blockIdx.x];
    const int dom = md.x;
    if (dom < 0) return;
    const int m0 = md.y;
    const int n0 = blockIdx.y * 128;

    __shared__ unsigned short As[128 * 32];
    __shared__ unsigned short Bs[128 * 32];

    const int tid = threadIdx.x;
    const int lane = tid & 63;
    const int w = tid >> 6;
    const int wr = w >> 1, wc = w & 1;
    const int c16 = lane & 15, quad = lane >> 4;

    const unsigned short* Abase = A + (size_t)m0 * DIN;
    const unsigned short* Bbase = Bt + (size_t)dom * DHID * DIN + (size_t)n0 * DIN;

    floatx4 acc[4][4];
#pragma unroll
    for (int i = 0; i < 4; i++)
#pragma unroll
        for (int j = 0; j < 4; j++) acc[i][j] = 0.f;

    for (int k0 = 0; k0 < DIN; k0 += 32) {
#pragma unroll
        for (int it = 0; it < 2; ++it) {
            const int c = w * 128 + it * 64 + lane;
            const int m = c >> 2, kc = c & 3;
            GLDS16(Abase + (size_t)m * DIN + k0 + kc * 8, &As[(w * 128 + it * 64) * 8]);
            GLDS16(Bbase + (size_t)m * DIN + k0 + kc * 8, &Bs[(w * 128 + it * 64) * 8]);
        }
        __syncthreads();

        short8 a[4], b[4];
        const int kk = quad * 8;
#pragma unroll
        for (int i = 0; i < 4; i++) {
            a[i] = *(const short8*)&As[(wr * 64 + i * 16 + c16) * 32 + kk];
            b[i] = *(const short8*)&Bs[(wc * 64 + i * 16 + c16) * 32 + kk];
        }
#pragma unroll
        for (int i = 0; i < 4; i++)
#pragma unroll
            for (int j = 0; j < 4; j++)
                acc[i][j] = __builtin_amdgcn_mfma_f32_16x16x32_bf16(a[i], b[j], acc[i][j], 0, 0, 0);
        __syncthreads();
    }

    float bv[4];
#pragma unroll
    for (int j = 0; j < 4; j++)
        bv[j] = bias[dom * DHID + n0 + wc * 64 + j * 16 + c16];

    float2* st = stats + (size_t)(blockIdx.y * 2 + wc) * MPAD;
#pragma unroll
    for (int i = 0; i < 4; i++) {
        const int rowbase = m0 + wr * 64 + i * 16 + quad * 4;
#pragma unroll
        for (int r = 0; r < 4; r++) {
            float s = 0.f, q = 0.f;
#pragma unroll
            for (int j = 0; j < 4; j++) {
                const float v = acc[i][j][r] + bv[j];
                const int col = n0 + wc * 64 + j * 16 + c16;
                H[(size_t)(rowbase + r) * DHID + col] = f2bf(v);
                s += v; q += v * v;
            }
#pragma unroll
            for (int o = 1; o < 16; o <<= 1) {   // reduce across 16 col lanes
                s += __shfl_xor(s, o, 64);
                q += __shfl_xor(q, o, 64);
            }
            if (c16 == 0) st[rowbase + r] = make_float2(s, q);
        }
    }
}

// ---------------- 4. GEMM-B with LN+ReLU fused into A-staging ----------------
__global__ __launch_bounds__(256, 2)
void gemm_b_ln(const unsigned short* __restrict__ H,   // [MPAD,1024] raw h+b1
               const unsigned short* __restrict__ Bt,  // W2T [ND,256,1024]
               const float* __restrict__ bias,         // b2 [ND,256]
               const float* __restrict__ gamma,
               const float* __restrict__ beta,
               const float2* __restrict__ stats,       // [16][MPAD]
               const int2* __restrict__ meta,
               const int* __restrict__ perm,
               float* __restrict__ out) {
    const int2 md = meta[blockIdx.x];
    const int dom = md.x;
    if (dom < 0) return;
    const int m0 = md.y;
    const int n0 = blockIdx.y * 128;

    __shared__ unsigned short As[128 * 32];
    __shared__ unsigned short Bs[128 * 32];
    __shared__ float mu_s[128], rs_s[128];

    const int tid = threadIdx.x;
    const int lane = tid & 63;
    const int w = tid >> 6;
    const int wr = w >> 1, wc = w & 1;
    const int c16 = lane & 15, quad = lane >> 4;

    // per-row LN constants from the 16 stat partials
    if (tid < 128) {
        float s = 0.f, q = 0.f;
#pragma unroll
        for (int cb = 0; cb < 16; cb++) {
            const float2 p = stats[(size_t)cb * MPAD + m0 + tid];
            s += p.x; q += p.y;
        }
        const float inv = 1.0f / (float)DHID;
        const float mu = s * inv;
        const float var = fmaxf(q * inv - mu * mu, 0.f);
        mu_s[tid] = mu;
        rs_s[tid] = rsqrtf(var + 1e-5f);
    }
    __syncthreads();

    const unsigned short* Hbase = H + (size_t)m0 * DHID;
    const unsigned short* Bbase = Bt + (size_t)dom * DOUT * DHID + (size_t)n0 * DHID;
    const float* gbase = gamma + dom * DHID;
    const float* bbase = beta + dom * DHID;

    floatx4 acc[4][4];
#pragma unroll
    for (int i = 0; i < 4; i++)
#pragma unroll
        for (int j = 0; j < 4; j++) acc[i][j] = 0.f;

    for (int k0 = 0; k0 < DHID; k0 += 32) {
        // ---- A: VGPR round-trip with LN+gamma/beta+ReLU, ds_write_b128 ----
#pragma unroll
        for (int it = 0; it < 2; ++it) {
            const int c = it * 256 + tid;            // 512 chunks of 8 elems
            const int row = c >> 2, kg = c & 3;
            const float mu = mu_s[row], rs = rs_s[row];
            const ushort8v hv = *(const ushort8v*)(Hbase + (size_t)row * DHID + k0 + kg * 8);
            const float4 g0 = *(const float4*)(gbase + k0 + kg * 8);
            const float4 g1 = *(const float4*)(gbase + k0 + kg * 8 + 4);
            const float4 b0 = *(const float4*)(bbase + k0 + kg * 8);
            const float4 b1 = *(const float4*)(bbase + k0 + kg * 8 + 4);
            float gg[8] = {g0.x, g0.y, g0.z, g0.w, g1.x, g1.y, g1.z, g1.w};
            float bb[8] = {b0.x, b0.y, b0.z, b0.w, b1.x, b1.y, b1.z, b1.w};
            ushort8v o;
#pragma unroll
            for (int e = 0; e < 8; e++) {
                const float v = (bf2f(hv[e]) - mu) * rs;
                o[e] = f2bf(fmaxf(v * gg[e] + bb[e], 0.f));
            }
            *(ushort8v*)&As[row * 32 + kg * 8] = o;   // contiguous: conflict-free
        }
        // ---- B: GLDS16 as before ----
#pragma unroll
        for (int it = 0; it < 2; ++it) {
            const int c = w * 128 + it * 64 + lane;
            const int m = c >> 2, kc = c & 3;
            GLDS16(Bbase + (size_t)m * DHID + k0 + kc * 8, &Bs[(w * 128 + it * 64) * 8]);
        }
        __syncthreads();

        short8 a[4], b[4];
        const int kk = quad * 8;
#pragma unroll
        for (int i = 0; i < 4; i++) {
            a[i] = *(const short8*)&As[(wr * 64 + i * 16 + c16) * 32 + kk];
            b[i] = *(const short8*)&Bs[(wc * 64 + i * 16 + c16) * 32 + kk];
        }
#pragma unroll
        for (int i = 0; i < 4; i++)
#pragma unroll
            for (int j = 0; j < 4; j++)
                acc[i][j] = __builtin_amdgcn_mfma_f32_16x16x32_bf16(a[i], b[j], acc[i][j], 0, 0, 0);
        __syncthreads();
    }

    // epilogue: scatter through perm (C/D layout col=lane&15, row=quad*4+reg)
#pragma unroll
    for (int i = 0; i < 4; i++) {
        const int rowbase = m0 + wr * 64 + i * 16 + quad * 4;
#pragma unroll
        for (int r = 0; r < 4; r++) {
            const int orig = perm[rowbase + r];
            if (orig < 0) continue;     // padding row
#pragma unroll
            for (int j = 0; j < 4; j++) {
                const int col = n0 + wc * 64 + j * 16 + c16;
                out[(size_t)orig * DOUT + col] = acc[i][j][r] + bias[dom * DOUT + col];
            }
        }
    }
}

// ---------------- launch ------------------------------------------------------
extern "C" void kernel_launch(void* const* d_in, const int* in_sizes, int n_in,
                              void* d_out, int out_size, void* d_ws, size_t ws_size,
                              hipStream_t stream) {
    const float* x = (const float*)d_in[0];
    const int* dt = (const int*)d_in[1];
    const float* W1 = (const float*)d_in[2];
    const float* b1 = (const float*)d_in[3];
    const float* gamma = (const float*)d_in[4];
    const float* beta = (const float*)d_in[5];
    const float* W2 = (const float*)d_in[6];
    const float* b2 = (const float*)d_in[7];
    float* out = (float*)d_out;

    char* ws = (char*)d_ws;
    size_t off = 0;
    auto take = [&](size_t nbytes) -> char* {
        char* p = ws + off;
        off = (off + nbytes + 255) & ~(size_t)255;
        return p;
    };
    unsigned short* W1T = (unsigned short*)take((size_t)ND * DHID * DIN * 2);
    unsigned short* W2T = (unsigned short*)take((size_t)ND * DOUT * DHID * 2);
    unsigned short* XS  = (unsigned short*)take((size_t)MPAD * DIN * 2);
    unsigned short* H   = (unsigned short*)take((size_t)MPAD * DHID * 2);
    float2* STATS = (float2*)take((size_t)16 * MPAD * 8);
    int* PERM   = (int*)take(MPAD * 4);
    int* POS    = (int*)take(NROWS * 4);
    int* CNT    = (int*)take(64);            // counts[8] then cursors[8]
    int2* META  = (int2*)take(NTILES * 8);
    (void)ws_size; (void)n_in; (void)in_sizes; (void)out_size;

    int* COUNTS = CNT;
    int* CURSORS = CNT + 8;

    transpose_bf16<<<dim3(DHID / 32, DIN / 32, ND), 256, 0, stream>>>(W1, W1T, DIN, DHID, CNT);
    transpose_bf16<<<dim3(DOUT / 32, DHID / 32, ND), 256, 0, stream>>>(W2, W2T, DHID, DOUT, nullptr);
    histo<<<NROWS / 256, 256, 0, stream>>>(dt, COUNTS);
    make_meta<<<1, 1, 0, stream>>>(COUNTS, CURSORS, META, PERM);
    assign_pos<<<NROWS / 256, 256, 0, stream>>>(dt, CURSORS, PERM, POS);
    copy_rows<<<NROWS / 4, 256, 0, stream>>>(x, POS, XS);
    gemm_a<<<dim3(NTILES, DHID / 128), 256, 0, stream>>>(XS, W1T, b1, META, H, STATS);
    gemm_b_ln<<<dim3(NTILES, DOUT / 128), 256, 0, stream>>>(
        H, W2T, b2, gamma, beta, STATS, META, PERM, out);
}